// Round 7
// baseline (186.933 us; speedup 1.0000x reference)
//
#include <hip/hip_runtime.h>
#include <stdint.h>

#define B_ 2048
#define T_ 256
#define V_ 128
#define E_ 128
#define H_ 64
#define G4_ 256  // 4*H
#define POS_W 20.0f
#define MB_ 8            // 8 rows/block: two independent 4-row groups (anti-phased)
#define NBLK_ (B_ / MB_) // 256 blocks x 512 thr = 1 block/CU, 2 waves/SIMD
typedef _Float16 half1;
typedef __attribute__((ext_vector_type(8))) _Float16 f16x8;
typedef __attribute__((ext_vector_type(4))) float f32x4;

#if __has_builtin(__builtin_amdgcn_exp2f)
#define EXP2F(x) __builtin_amdgcn_exp2f(x)
#else
#define EXP2F(x) exp2f(x)
#endif

#if __has_builtin(__builtin_amdgcn_rcpf)
#define RCPF(x) __builtin_amdgcn_rcpf(x)
#else
#define RCPF(x) (1.0f / (x))
#endif

#define L2E 1.44269504f

// Barrier draining ONLY lgkmcnt: keeps L2 proj-prefetches (vmcnt) in flight
// across phase boundaries. In-flight global loads only write registers.
__device__ __forceinline__ void lds_barrier() {
    asm volatile("s_waitcnt lgkmcnt(0)\n\ts_barrier" ::: "memory");
}

// ---------------------------------------------------------------------------
// k_prep: projC[v][u][g] = dot(emb[v], W_ih[g*64+u]) + b_ih + b_hh   (f32)
// ---------------------------------------------------------------------------
__global__ void k_prep(const float* __restrict__ emb, const float* __restrict__ Wih,
                       const float* __restrict__ bih, const float* __restrict__ bhh,
                       float* __restrict__ projC, float* __restrict__ loss_slot) {
    int tid = threadIdx.x;  // 0..255; u = tid>>2, g = tid&3
    int v = blockIdx.x;
    if (v == 0 && tid == 0) *loss_slot = 0.0f;
    int u = tid >> 2, g = tid & 3;
    int row = g * 64 + u;
    const float4* e4 = (const float4*)(emb + v * E_);
    const float4* w4 = (const float4*)(Wih + row * E_);
    float acc = bih[row] + bhh[row];
#pragma unroll
    for (int i = 0; i < E_ / 4; ++i) {
        float4 a = e4[i];
        float4 b = w4[i];
        acc += a.x * b.x + a.y * b.y + a.z * b.z + a.w * b.w;
    }
    projC[v * G4_ + tid] = acc;  // coalesced
}

// ---------------------------------------------------------------------------
// k_lstm R15: DETERMINISTIC ANTI-PHASE role-split.
// Ledger (cyc/SIMD/step): per-cell VALU-busy ~240 invariant; MFMA ~16 cyc ea.
//   R4 (2 waves/SIMD, stochastic overlap): 260 MFMA + 490 VALU + 140 = 890
//   R6 (1 wave/SIMD): 128 MFMA + 490 VALU + 350 naked stall = 969
// Fix: one 512-thr block/CU, TWO independent 4-row groups (g = w>>2).
// Each step = two barrier-delimited half-phases; group roles alternate:
//   half1: g0 {ds_read h, 8 MFMA issue, prefetch+prescale} | g1 {cell VALU}
//   half2: roles swapped
// Every SIMD always has one wave in mem/MFMA role + one in VALU role —
// overlap is enforced by the barrier, not left to scheduler luck.
// Stagger bonus: MFMA results consumed a half-phase after issue (latency
// hidden); each group's h write->read are in adjacent halves => SINGLE
// h buffer per group (no double-buffering).
// ---------------------------------------------------------------------------
__launch_bounds__(512, 1)
__global__ void k_lstm(const int* __restrict__ x, const float* __restrict__ Whh,
                       const float* __restrict__ projC, const float* __restrict__ Wfc,
                       const float* __restrict__ bfc, const float* __restrict__ targets,
                       float* __restrict__ logits, float* __restrict__ loss_slot) {
    int b0 = blockIdx.x * MB_;
    int t = threadIdx.x;         // 0..511
    int w = t >> 6, l = t & 63;  // wave, lane
    int g = w >> 2, wg = w & 3;  // group, wave-in-group
    int q = l >> 4, cc = l & 15;
    int u = 16 * wg + cc;        // unit owned by this lane (all 4 gates)
    int r = g * 4 + q;           // batch row within block

    __shared__ __align__(16) half1 hf[2][1024];  // one h buffer PER GROUP
    __shared__ int xT[T_][MB_];                  // token byte-offsets (tok<<10)
    __shared__ float hfin[MB_][68];              // final h (padded)
    __shared__ float zred[MB_];

    // stage xT; pre-scale to byte offset
    for (int i = t; i < T_ * MB_; i += 512) {
        int tt = i >> 3, rr = i & 7;
        xT[tt][rr] = x[(b0 + rr) * T_ + tt] << 10;  // *G4_*4
    }
    ((float*)hf)[t] = 0.0f;  // 1024 floats = both groups' h buffers
    ((float*)hf)[t + 512] = 0.0f;
    __syncthreads();

    // B-fragments inline from W_hh (f32, L2): N-tile jj, K-chunk c.
    // frag elem j: B[k=c*32+q*8+j][col cc] = Whh[jj*64+16wg+cc][k]
    f16x8 bf[4][2];
#pragma unroll
    for (int jj = 0; jj < 4; ++jj) {
#pragma unroll
        for (int c = 0; c < 2; ++c) {
            int row = jj * 64 + 16 * wg + cc;
            int kb = c * 32 + q * 8;
            float4 w0 = *(const float4*)(Whh + row * H_ + kb);
            float4 w1 = *(const float4*)(Whh + row * H_ + kb + 4);
            f16x8 tmp;
            tmp[0] = (half1)w0.x; tmp[1] = (half1)w0.y;
            tmp[2] = (half1)w0.z; tmp[3] = (half1)w0.w;
            tmp[4] = (half1)w1.x; tmp[5] = (half1)w1.y;
            tmp[6] = (half1)w1.z; tmp[7] = (half1)w1.w;
            bf[jj][c] = tmp;
        }
    }

    // h-write slot for (unit u, M-row 4q) within this group's buffer
    int hbase = (u >> 5) * 512 + ((u >> 3) & 3) * 128 + (4 * q) * 8 + (u & 7);

    float creg = 0.0f, hreg = 0.0f;
    const char* pcb = (const char*)projC;
    int uoff = u << 4;  // u*16 bytes

    // proj pipeline (depth 2) for this lane's row r
    f32x4 pp = *(const f32x4*)(pcb + xT[0][r] + uoff);
    f32x4 pn = *(const f32x4*)(pcb + xT[1][r] + uoff);
    int xc = xT[2][r];

    f32x4 d0[4], d1[4];
    float psx = 0.f, psy = 0.f, pgz = 0.f, psw = 0.f;
    const f32x4 z4 = {0.0f, 0.0f, 0.0f, 0.0f};

#define MFMA_HALF(STEP_)                                                              \
    do {                                                                              \
        const f16x8 a0 = *(const f16x8*)(hf[g] + l * 8);                              \
        const f16x8 a1 = *(const f16x8*)(hf[g] + 512 + l * 8);                        \
        _Pragma("unroll") for (int jj = 0; jj < 4; ++jj) {                            \
            d0[jj] = __builtin_amdgcn_mfma_f32_16x16x32_f16(a0, bf[jj][0], z4, 0, 0, 0); \
            d1[jj] = __builtin_amdgcn_mfma_f32_16x16x32_f16(a1, bf[jj][1], z4, 0, 0, 0); \
        }                                                                             \
        f32x4 p2 = *(const f32x4*)(pcb + xc + uoff);                                  \
        int xn = xT[((STEP_) + 3) & (T_ - 1)][r];                                     \
        psx = -L2E * pp.x;                                                            \
        psy = -L2E * pp.y;                                                            \
        pgz = 2.0f * L2E * pp.z;                                                      \
        psw = -L2E * pp.w;                                                            \
        pp = pn; pn = p2; xc = xn;                                                    \
    } while (0)

#define CELL_HALF()                                                                   \
    do {                                                                              \
        float g0v = d0[0][0] + d1[0][0];                                              \
        float g1v = d0[1][0] + d1[1][0];                                              \
        float g2v = d0[2][0] + d1[2][0];                                              \
        float g3v = d0[3][0] + d1[3][0];                                              \
        float ei = EXP2F(__builtin_fmaf(-L2E, g0v, psx));                             \
        float ef = EXP2F(__builtin_fmaf(-L2E, g1v, psy));                             \
        float eg = EXP2F(__builtin_fmaf(2.0f * L2E, g2v, pgz));                       \
        float eo = EXP2F(__builtin_fmaf(-L2E, g3v, psw));                             \
        float i_ = RCPF(1.0f + ei);                                                   \
        float f_ = RCPF(1.0f + ef);                                                   \
        float tg = 1.0f - 2.0f * RCPF(eg + 1.0f);                                     \
        float o_ = RCPF(1.0f + eo);                                                   \
        creg = __builtin_fmaf(f_, creg, i_ * tg);                                     \
        float et = EXP2F(2.0f * L2E * creg);                                          \
        hreg = o_ * (1.0f - 2.0f * RCPF(et + 1.0f));                                  \
        hf[g][hbase] = (half1)hreg;                                                   \
    } while (0)

    // Schedule: g0 step s = {half1: MFMA(s), half2: CELL(s)};
    //           g1 step s = {half2: MFMA(s), next half1: CELL(s)}.
    for (int step = 0; step < T_; ++step) {
        if (g == 0) {
            MFMA_HALF(step);
        } else if (step) {
            CELL_HALF();
        }
        lds_barrier();
        if (g == 0) {
            CELL_HALF();
        } else {
            MFMA_HALF(step);
        }
        lds_barrier();
    }
    if (g == 1) CELL_HALF();  // finish step T-1

    // epilogue: logits + fused loss
    hfin[r][u] = hreg;
    __syncthreads();
    // wave w reduces batch row w (8 waves = 8 rows)
    float part = hfin[w][l] * Wfc[l];
#pragma unroll
    for (int off = 32; off > 0; off >>= 1) part += __shfl_down(part, off, 64);
    if (l == 0) {
        float z = part + bfc[0];
        logits[b0 + w] = z;
        float tg = targets[b0 + w];
        float e = EXP2F(-L2E * fabsf(z));
        float lsp = fminf(z, 0.0f) - log1pf(e);
        float lsn = lsp - z;
        zred[w] = -(POS_W * tg * lsp + (1.0f - tg) * lsn) * (1.0f / (float)B_);
    }
    __syncthreads();
    if (t == 0) {
        float s = 0.0f;
#pragma unroll
        for (int i = 0; i < MB_; ++i) s += zred[i];
        atomicAdd(loss_slot, s);
    }
#undef MFMA_HALF
#undef CELL_HALF
}

// ---------------------------------------------------------------------------
extern "C" void kernel_launch(void* const* d_in, const int* in_sizes, int n_in,
                              void* d_out, int out_size, void* d_ws, size_t ws_size,
                              hipStream_t stream) {
    const int* x = (const int*)d_in[0];
    const float* targets = (const float*)d_in[1];
    const float* emb = (const float*)d_in[2];
    const float* Wih = (const float*)d_in[3];
    const float* Whh = (const float*)d_in[4];
    const float* bih = (const float*)d_in[5];
    const float* bhh = (const float*)d_in[6];
    const float* Wfc = (const float*)d_in[7];
    const float* bfc = (const float*)d_in[8];
    float* out = (float*)d_out;  // [0..2047] logits, [2048] loss

    float* projC = (float*)d_ws;  // 128*256*4 = 128 KiB

    k_prep<<<dim3(V_), dim3(256), 0, stream>>>(emb, Wih, bih, bhh, projC, out + B_);
    k_lstm<<<dim3(NBLK_), dim3(512), 0, stream>>>(x, Whh, projC, Wfc, bfc, targets, out,
                                                  out + B_);
}

// Round 8
// 155.071 us; speedup vs baseline: 1.2055x; 1.2055x over previous
//
#include <hip/hip_runtime.h>
#include <stdint.h>

#define B_ 2048
#define T_ 256
#define V_ 128
#define E_ 128
#define H_ 64
#define G4_ 256  // 4*H
#define POS_W 20.0f
#define MB_ 4            // batch rows per block: row j at M-row 4j (C-reg[0] of lane quad j)
#define NBLK_ (B_ / MB_) // 512 blocks = 2 blocks/CU = 2 waves/SIMD
typedef _Float16 half1;
typedef __attribute__((ext_vector_type(8))) _Float16 f16x8;
typedef __attribute__((ext_vector_type(4))) float f32x4;

#if __has_builtin(__builtin_amdgcn_exp2f)
#define EXP2F(x) __builtin_amdgcn_exp2f(x)
#else
#define EXP2F(x) exp2f(x)
#endif

#if __has_builtin(__builtin_amdgcn_rcpf)
#define RCPF(x) __builtin_amdgcn_rcpf(x)
#else
#define RCPF(x) (1.0f / (x))
#endif

#define L2E 1.44269504f

// Barrier draining ONLY lgkmcnt: keeps L2 proj-prefetches (vmcnt) in flight
// across the step boundary. Safe: h-exchange is double-buffered; in-flight
// global loads only write registers.
__device__ __forceinline__ void lds_barrier() {
    asm volatile("s_waitcnt lgkmcnt(0)\n\ts_barrier" ::: "memory");
}

// ---------------------------------------------------------------------------
// k_prep: projC[v][u][g] = dot(emb[v], W_ih[g*64+u]) + b_ih + b_hh   (f32)
// ---------------------------------------------------------------------------
__global__ void k_prep(const float* __restrict__ emb, const float* __restrict__ Wih,
                       const float* __restrict__ bih, const float* __restrict__ bhh,
                       float* __restrict__ projC, float* __restrict__ loss_slot) {
    int tid = threadIdx.x;  // 0..255; u = tid>>2, g = tid&3
    int v = blockIdx.x;
    if (v == 0 && tid == 0) *loss_slot = 0.0f;
    int u = tid >> 2, g = tid & 3;
    int row = g * 64 + u;
    const float4* e4 = (const float4*)(emb + v * E_);
    const float4* w4 = (const float4*)(Wih + row * E_);
    float acc = bih[row] + bhh[row];
#pragma unroll
    for (int i = 0; i < E_ / 4; ++i) {
        float4 a = e4[i];
        float4 b = w4[i];
        acc += a.x * b.x + a.y * b.y + a.z * b.z + a.w * b.w;
    }
    projC[v * G4_ + tid] = acc;  // coalesced
}

// ---------------------------------------------------------------------------
// k_lstm R16: R4 structure (proven 890 cyc/step) + MERGED-RCP CELL.
// Ledger: VALU ~480/SIMD/step is trans-dominated (10 trans/cell at ~16cyc).
// Algebra: put the cell over common denominators ->
//   c' = [c*(1+ei)(eg+1) + (eg-1)(1+ef)] * rcp((1+ei)(eg+1)(1+ef))
//   h  = (et-1) * rcp((1+eo)(et+1)),  et = exp2(2*L2E*clamp(c',+-15))
// 5 exp2 + 2 rcp = 7 trans (was 10): -3 rcp issue + 2 fewer dependent
// trans levels on the serial chain, +~6 cheap muls. Gate args bounded
// ~+-6 by data -> products <= ~1e10; clamp keeps et finite. No inf/NaN.
// Everything else byte-identical to the verified R4 kernel.
// ---------------------------------------------------------------------------
__launch_bounds__(256, 2)
__global__ void k_lstm(const int* __restrict__ x, const float* __restrict__ Whh,
                       const float* __restrict__ projC, const float* __restrict__ Wfc,
                       const float* __restrict__ bfc, const float* __restrict__ targets,
                       float* __restrict__ logits, float* __restrict__ loss_slot) {
    int b0 = blockIdx.x * MB_;
    int t = threadIdx.x;         // 0..255
    int w = t >> 6, l = t & 63;  // wave, lane
    int q = l >> 4, cc = l & 15;
    int u = 16 * w + cc;  // unit owned by this lane (all 4 gates), batch row q

    __shared__ __align__(16) half1 hf[2][1024];  // A-layout h, double-buffered
    __shared__ int xT[T_][MB_];                  // token byte-offsets (tok<<10)
    __shared__ float hfin[MB_][68];              // final h (padded)
    __shared__ float zred[MB_];

    // stage xT (coalesced: fixed i, consecutive t); pre-scale to byte offset
#pragma unroll
    for (int i = 0; i < MB_; ++i) xT[t][i] = x[(b0 + i) * T_ + t] << 10;  // *G4_*4
    ((float*)hf)[t] = 0.0f;
    ((float*)hf)[t + 256] = 0.0f;
    ((float*)hf)[t + 512] = 0.0f;
    ((float*)hf)[t + 768] = 0.0f;
    __syncthreads();

    // B-fragments inline from W_hh (f32, L2): N-tile jj, K-chunk c.
    // frag elem j: B[k=c*32+q*8+j][col cc] = Whh[jj*64+16w+cc][k]  (R5-R8 verified)
    f16x8 bf[4][2];
#pragma unroll
    for (int jj = 0; jj < 4; ++jj) {
#pragma unroll
        for (int c = 0; c < 2; ++c) {
            int row = jj * 64 + 16 * w + cc;
            int kb = c * 32 + q * 8;
            float4 w0 = *(const float4*)(Whh + row * H_ + kb);
            float4 w1 = *(const float4*)(Whh + row * H_ + kb + 4);
            f16x8 tmp;
            tmp[0] = (half1)w0.x; tmp[1] = (half1)w0.y;
            tmp[2] = (half1)w0.z; tmp[3] = (half1)w0.w;
            tmp[4] = (half1)w1.x; tmp[5] = (half1)w1.y;
            tmp[6] = (half1)w1.z; tmp[7] = (half1)w1.w;
            bf[jj][c] = tmp;
        }
    }

    // h-write slot for (unit u, M-row 4q):
    // f16 idx = (u>>5)*512 + ((u>>3)&3)*128 + (4q)*8 + (u&7)
    int hbase = (u >> 5) * 512 + ((u >> 3) & 3) * 128 + (4 * q) * 8 + (u & 7);

    float cA = 0.0f, hA = 0.0f;
    const char* pcb = (const char*)projC;
    int uoff = u << 4;  // u*16 bytes

    // prefetch proj for steps 0 and 1 (depth 2); same-q lanes broadcast-read xT
    f32x4 ppA = *(const f32x4*)(pcb + xT[0][q] + uoff);
    f32x4 pnA = *(const f32x4*)(pcb + xT[1][q] + uoff);
    int xcA = xT[2][q];  // token byte-offset for step+2's proj load

    const f32x4 z4 = {0.0f, 0.0f, 0.0f, 0.0f};
    int p = 0;
#pragma unroll 2
    for (int step = 0; step < T_; ++step) {
        // ---- chain head: A-fragments of h_t (conflict-free lane-contiguous b128)
        const f16x8 a0 = *(const f16x8*)(hf[p] + l * 8);
        const f16x8 a1 = *(const f16x8*)(hf[p] + 512 + l * 8);

        // gates for (row q, unit u): only C-reg[0] live. pp folded into C of d0;
        // K-chunk MFMAs independent (unchained) -> single MFMA latency + 1 add.
        float gA[4];
#pragma unroll
        for (int jj = 0; jj < 4; ++jj) {
            f32x4 c4 = z4;
            c4[0] = ppA[jj];
            f32x4 d0 = __builtin_amdgcn_mfma_f32_16x16x32_f16(a0, bf[jj][0], c4, 0, 0, 0);
            f32x4 d1 = __builtin_amdgcn_mfma_f32_16x16x32_f16(a1, bf[jj][1], z4, 0, 0, 0);
            gA[jj] = d0[0] + d1[0];
        }

        // ---- off-chain: prefetch (issues while MFMAs are in flight)
        f32x4 p2A = *(const f32x4*)(pcb + xcA + uoff);           // proj for step+2
        int xnA = xT[(step + 3) & (T_ - 1)][q];                  // token for step+3

        // ---- chain tail: merged-rcp cell (5 exp2 + 2 rcp, was 10 trans)
        float ei = EXP2F(-L2E * gA[0]);         // e^{-i_arg}
        float ef = EXP2F(-L2E * gA[1]);         // e^{-f_arg}
        float eg = EXP2F(2.0f * L2E * gA[2]);   // e^{2 g_arg}
        float eo = EXP2F(-L2E * gA[3]);         // e^{-o_arg}

        float onei = 1.0f + ei;
        float oneg = eg + 1.0f;
        float onef = 1.0f + ef;
        float P = onei * oneg;                  // (1+ei)(eg+1)
        float D1 = P * onef;
        float N1 = __builtin_fmaf(cA, P, (eg - 1.0f) * onef);
        cA = N1 * RCPF(D1);

        float ct = fminf(fmaxf(cA, -15.0f), 15.0f);
        float et = EXP2F(2.0f * L2E * ct);      // e^{2c}
        float D2 = (1.0f + eo) * (et + 1.0f);
        hA = (et - 1.0f) * RCPF(D2);

        // publish h_{t+1} (A-layout, other buffer)
        hf[p ^ 1][hbase] = (half1)hA;

        ppA = pnA;
        pnA = p2A;
        xcA = xnA;
        p ^= 1;
        lds_barrier();  // lgkmcnt-only: proj prefetches stay in flight
    }

    // epilogue: logits + fused loss
    hfin[q][u] = hA;
    __syncthreads();
    int m4 = t >> 6, uu = t & 63;  // wave m4 reduces batch row m4
    float part = hfin[m4][uu] * Wfc[uu];
#pragma unroll
    for (int off = 32; off > 0; off >>= 1) part += __shfl_down(part, off, 64);
    if (uu == 0) {
        float z = part + bfc[0];
        logits[b0 + m4] = z;
        float tg = targets[b0 + m4];
        float e = EXP2F(-L2E * fabsf(z));
        float lsp = fminf(z, 0.0f) - log1pf(e);
        float lsn = lsp - z;
        zred[m4] = -(POS_W * tg * lsp + (1.0f - tg) * lsn) * (1.0f / (float)B_);
    }
    __syncthreads();
    if (t == 0) {
        float s = 0.0f;
#pragma unroll
        for (int i = 0; i < MB_; ++i) s += zred[i];
        atomicAdd(loss_slot, s);
    }
}

// ---------------------------------------------------------------------------
extern "C" void kernel_launch(void* const* d_in, const int* in_sizes, int n_in,
                              void* d_out, int out_size, void* d_ws, size_t ws_size,
                              hipStream_t stream) {
    const int* x = (const int*)d_in[0];
    const float* targets = (const float*)d_in[1];
    const float* emb = (const float*)d_in[2];
    const float* Wih = (const float*)d_in[3];
    const float* Whh = (const float*)d_in[4];
    const float* bih = (const float*)d_in[5];
    const float* bhh = (const float*)d_in[6];
    const float* Wfc = (const float*)d_in[7];
    const float* bfc = (const float*)d_in[8];
    float* out = (float*)d_out;  // [0..2047] logits, [2048] loss

    float* projC = (float*)d_ws;  // 128*256*4 = 128 KiB

    k_prep<<<dim3(V_), dim3(256), 0, stream>>>(emb, Wih, bih, bhh, projC, out + B_);
    k_lstm<<<dim3(NBLK_), dim3(256), 0, stream>>>(x, Whh, projC, Wfc, bfc, targets, out,
                                                  out + B_);
}